// Round 1
// baseline (437.016 us; speedup 1.0000x reference)
//
#include <hip/hip_runtime.h>

// LIF scan over trailing time axis T=16.
// X: [B=32, C=128, H=32, W=32, T=16] fp32, T contiguous (stride 1).
// mem = mem*0.5 + x_t; s = (mem >= 1.0); mem = mem*(1-s)  [hard reset]
// One thread owns one pixel's 16 contiguous timesteps: 4x float4 load,
// fully unrolled register scan, 4x float4 store. Memory-bound (~536 MB).

#define LIF_DECAY  0.5f
#define LIF_THRESH 1.0f

__global__ __launch_bounds__(256) void lif_kernel(const float* __restrict__ X,
                                                  float* __restrict__ out,
                                                  int n_pixels) {
    int p = blockIdx.x * blockDim.x + threadIdx.x;
    if (p >= n_pixels) return;

    const float4* __restrict__ xin = reinterpret_cast<const float4*>(X) + (size_t)p * 4;
    float4* __restrict__ oout      = reinterpret_cast<float4*>(out) + (size_t)p * 4;

    float4 v0 = xin[0];
    float4 v1 = xin[1];
    float4 v2 = xin[2];
    float4 v3 = xin[3];

    float x[16] = {v0.x, v0.y, v0.z, v0.w,
                   v1.x, v1.y, v1.z, v1.w,
                   v2.x, v2.y, v2.z, v2.w,
                   v3.x, v3.y, v3.z, v3.w};
    float s[16];

    float mem = 0.0f;
#pragma unroll
    for (int t = 0; t < 16; ++t) {
        mem = mem * LIF_DECAY + x[t];
        float spike = (mem >= LIF_THRESH) ? 1.0f : 0.0f;
        s[t] = spike;
        mem = (spike != 0.0f) ? 0.0f : mem;   // hard reset on spike
    }

    oout[0] = make_float4(s[0],  s[1],  s[2],  s[3]);
    oout[1] = make_float4(s[4],  s[5],  s[6],  s[7]);
    oout[2] = make_float4(s[8],  s[9],  s[10], s[11]);
    oout[3] = make_float4(s[12], s[13], s[14], s[15]);
}

extern "C" void kernel_launch(void* const* d_in, const int* in_sizes, int n_in,
                              void* d_out, int out_size, void* d_ws, size_t ws_size,
                              hipStream_t stream) {
    (void)n_in; (void)d_ws; (void)ws_size; (void)out_size;
    const float* X = (const float*)d_in[0];
    float* out = (float*)d_out;

    const int T = 16;
    int n_pixels = in_sizes[0] / T;   // 4,194,304

    const int block = 256;
    int grid = (n_pixels + block - 1) / block;
    lif_kernel<<<grid, block, 0, stream>>>(X, out, n_pixels);
}

// Round 2
// 427.700 us; speedup vs baseline: 1.0218x; 1.0218x over previous
//
#include <hip/hip_runtime.h>

// LIF scan over trailing time axis T=16.
// X: [4194304 pixels][16 timesteps] fp32, T contiguous.
//
// R1 lesson: thread-per-pixel direct loads have 64 B lane stride ->
// every global_load_dwordx4 touches 64 distinct cache lines (4x the
// request rate of coalesced) -> 1.23 TB/s. Fix: coalesced float4
// global access + LDS transpose to pixel-private order and back.
//
// LDS layout: float4 lds[quarter*257 + pixel_local]; the 257 pad makes
// both phases hit 8 lanes per bank-quad (structural minimum for b128).

#define LIF_DECAY  0.5f
#define LIF_THRESH 1.0f

// One LIF step on one float, in place. v holds x_t on entry, spike on exit.
#define LIF_STEP(v)                                        \
    {                                                      \
        m = m * LIF_DECAY + (v);                           \
        float sp = (m >= LIF_THRESH) ? 1.0f : 0.0f;        \
        (v) = sp;                                          \
        m = (sp != 0.0f) ? 0.0f : m;                       \
    }

__global__ __launch_bounds__(256) void lif_kernel(const float4* __restrict__ X4,
                                                  float4* __restrict__ O4) {
    // 256 threads, 256 pixels/block, 1024 float4 per block.
    __shared__ float4 lds[4 * 257];

    const int tid = threadIdx.x;
    const size_t base = (size_t)blockIdx.x * 1024;

    const int q  = tid & 3;          // quarter owned during coalesced phases
    const int plc = (tid >> 2);      // pixel_local base for coalesced phases

    // ---- Phase 1: coalesced global load -> LDS (transposed) ----
#pragma unroll
    for (int k = 0; k < 4; ++k) {
        float4 v = X4[base + (size_t)(k * 256 + tid)];
        // float4 index m = k*256+tid: pixel_local = m>>2 = k*64+(tid>>2), quarter = tid&3
        lds[q * 257 + (k * 64 + plc)] = v;
    }
    __syncthreads();

    // ---- Phase 2: pixel-private read, register scan ----
    float4 f0 = lds[0 * 257 + tid];
    float4 f1 = lds[1 * 257 + tid];
    float4 f2 = lds[2 * 257 + tid];
    float4 f3 = lds[3 * 257 + tid];

    float m = 0.0f;
    LIF_STEP(f0.x) LIF_STEP(f0.y) LIF_STEP(f0.z) LIF_STEP(f0.w)
    LIF_STEP(f1.x) LIF_STEP(f1.y) LIF_STEP(f1.z) LIF_STEP(f1.w)
    LIF_STEP(f2.x) LIF_STEP(f2.y) LIF_STEP(f2.z) LIF_STEP(f2.w)
    LIF_STEP(f3.x) LIF_STEP(f3.y) LIF_STEP(f3.z) LIF_STEP(f3.w)

    __syncthreads();   // all reads done before LDS reuse

    // ---- Phase 3: spikes -> LDS (pixel-private write) ----
    lds[0 * 257 + tid] = f0;
    lds[1 * 257 + tid] = f1;
    lds[2 * 257 + tid] = f2;
    lds[3 * 257 + tid] = f3;
    __syncthreads();

    // ---- Phase 4: coalesced global store ----
#pragma unroll
    for (int k = 0; k < 4; ++k) {
        O4[base + (size_t)(k * 256 + tid)] = lds[q * 257 + (k * 64 + plc)];
    }
}

extern "C" void kernel_launch(void* const* d_in, const int* in_sizes, int n_in,
                              void* d_out, int out_size, void* d_ws, size_t ws_size,
                              hipStream_t stream) {
    (void)n_in; (void)d_ws; (void)ws_size; (void)out_size;
    const float4* X4 = (const float4*)d_in[0];
    float4* O4 = (float4*)d_out;

    // 67,108,864 floats = 16,777,216 float4 = 16384 blocks x 1024 float4.
    int n_f4 = in_sizes[0] / 4;
    int grid = n_f4 / 1024;          // exact: 16384
    lif_kernel<<<grid, 256, 0, stream>>>(X4, O4);
}